// Round 5
// baseline (266.072 us; speedup 1.0000x reference)
//
#include <hip/hip_runtime.h>
#include <hip/hip_bf16.h>

// ContrastiveLoss on MI355X.
// ws layout (requires ws_size >= 8MB + 96KB):
//   [0, 4MB)        xn bf16 [8192][256]
//   [4MB, 8MB)      yn bf16 [8192][256]
//   [8MB, 8MB+96KB) rowsum f32 [3][8192]

#define N_ROWS 8192
#define DIM 256
#define EPSF 1e-8f
#define BM 128
#define BK 64

typedef __attribute__((ext_vector_type(8))) short bf16x8;
typedef __attribute__((ext_vector_type(4))) float f32x4;
typedef __attribute__((ext_vector_type(4))) short short4v;

__device__ __forceinline__ short f2bf(float f) {
  unsigned u = __float_as_uint(f);
  unsigned r = (u + 0x7fffu + ((u >> 16) & 1u)) >> 16;  // RNE
  return (short)r;
}

__device__ __forceinline__ float bf2f(short s) {
  return __uint_as_float(((unsigned)(unsigned short)s) << 16);
}

typedef const __attribute__((address_space(1))) void g_void;
typedef __attribute__((address_space(3))) void s_void;

__device__ __forceinline__ void gld_lds16(const void* g, void* l) {
  __builtin_amdgcn_global_load_lds((g_void*)g, (s_void*)l, 16, 0, 0);
}

// ---------------- Kernel 1: row-normalize x,y -> bf16 ----------------
__global__ void k_normalize(const float* __restrict__ x, const float* __restrict__ y,
                            short* __restrict__ xn, short* __restrict__ yn) {
  int wave = threadIdx.x >> 6;
  int lane = threadIdx.x & 63;
  int row = blockIdx.x * 4 + wave;  // 0..16383
  const float* src;
  short* dst;
  int r;
  if (row < N_ROWS) { src = x; dst = xn; r = row; }
  else              { src = y; dst = yn; r = row - N_ROWS; }
  const float4 v = *(const float4*)(src + r * DIM + lane * 4);
  float ss = v.x * v.x + v.y * v.y + v.z * v.z + v.w * v.w;
  #pragma unroll
  for (int m = 1; m < 64; m <<= 1) ss += __shfl_xor(ss, m, 64);
  float scale = 1.0f / (sqrtf(ss) + EPSF);
  short4v o;
  o.x = f2bf(v.x * scale);
  o.y = f2bf(v.y * scale);
  o.z = f2bf(v.z * scale);
  o.w = f2bf(v.w * scale);
  *(short4v*)(dst + r * DIM + lane * 4) = o;
}

// ------- Kernel 2: sim tile (bf16 MFMA) + exp + row-partial sums -------
// grid = 3 * 64 * 64 = 12288 blocks, 256 threads (4 waves, wave tile 64x64).
// Pairs 0 (xx) and 2 (yy) are symmetric: blocks with nb < mb exit early;
// off-diagonal upper blocks (nb > mb) also contribute their COLUMN sums
// (= transposed block's row sums) to rowsum[nb-rows].
__global__ __launch_bounds__(256, 3) void k_gemm(const short* __restrict__ xn,
                                                 const short* __restrict__ yn,
                                                 float* __restrict__ rowsum) {
  __shared__ __align__(16) short As[BM * BK];
  __shared__ __align__(16) short Bs[BM * BK];
  __shared__ float redbuf[256];  // [0:128) row partials, [128:256) col partials

  // XCD-chunked bijective swizzle (12288 % 8 == 0)
  int bid = blockIdx.x;
  int per = gridDim.x >> 3;                 // 1536
  int swz = (bid & 7) * per + (bid >> 3);
  int pair = swz >> 12;                     // / 4096
  int t = swz & 4095;
  int mb = t >> 6, nb = t & 63;

  bool sym = (pair != 1);
  if (sym && nb < mb) return;               // block-uniform exit (before any barrier)

  const short* Ap = (pair == 2) ? yn : xn;
  const short* Bp = (pair == 0) ? xn : yn;
  const short* Abase = Ap + mb * BM * DIM;
  const short* Bbase = Bp + nb * BM * DIM;

  int tid = threadIdx.x;
  int lane = tid & 63;
  int wid = tid >> 6;
  int wm = wid >> 1, wn = wid & 1;

  redbuf[tid] = 0.f;  // zero reduction scratch (barrier before use is in epilogue)

  f32x4 acc[4][4];
  #pragma unroll
  for (int i = 0; i < 4; ++i)
    #pragma unroll
    for (int j = 0; j < 4; ++j) acc[i][j] = (f32x4){0.f, 0.f, 0.f, 0.f};

  for (int ks = 0; ks < DIM / BK; ++ks) {
    // stage A,B tiles [128][64] bf16 (16KB each) via global_load_lds x16B.
    // dest = wave-uniform base (i*256+w*64)*16 + lane*16  (m104 semantics ok)
    #pragma unroll
    for (int i = 0; i < 4; ++i) {
      int s = i * 256 + tid;       // 16B slot id, 1024 slots per tile
      int row = s >> 3, c = s & 7;
      gld_lds16(Abase + row * DIM + ks * BK + c * 8, As + s * 8);
      gld_lds16(Bbase + row * DIM + ks * BK + c * 8, Bs + s * 8);
    }
    __syncthreads();
    #pragma unroll
    for (int kk = 0; kk < 2; ++kk) {
      bf16x8 a[4], b[4];
      #pragma unroll
      for (int mi = 0; mi < 4; ++mi)
        a[mi] = *(const bf16x8*)(As + (wm * 64 + mi * 16 + (lane & 15)) * BK + kk * 32 + (lane >> 4) * 8);
      #pragma unroll
      for (int ni = 0; ni < 4; ++ni)
        b[ni] = *(const bf16x8*)(Bs + (wn * 64 + ni * 16 + (lane & 15)) * BK + kk * 32 + (lane >> 4) * 8);
      #pragma unroll
      for (int mi = 0; mi < 4; ++mi)
        #pragma unroll
        for (int ni = 0; ni < 4; ++ni)
          acc[mi][ni] = __builtin_amdgcn_mfma_f32_16x16x32_bf16(a[mi], b[ni], acc[mi][ni], 0, 0, 0);
    }
    __syncthreads();
  }

  // epilogue: exp in place, then row sums (and col sums for sym off-diag)
  // C layout: col = lane&15, row = (lane>>4)*4 + r  (m89-verified)
  // C global coords: row = mb*128 + wm*64 + mi*16 + (lane>>4)*4 + r
  //                  col = nb*128 + wn*64 + ni*16 + (lane&15)
  #pragma unroll
  for (int mi = 0; mi < 4; ++mi)
    #pragma unroll
    for (int ni = 0; ni < 4; ++ni)
      #pragma unroll
      for (int r = 0; r < 4; ++r)
        acc[mi][ni][r] = __expf(acc[mi][ni][r]);

  // row sums: sum over ni, then reduce across the 16 col-lanes
  float rs[4][4];
  #pragma unroll
  for (int mi = 0; mi < 4; ++mi)
    #pragma unroll
    for (int r = 0; r < 4; ++r)
      rs[mi][r] = acc[mi][0][r] + acc[mi][1][r] + acc[mi][2][r] + acc[mi][3][r];
  #pragma unroll
  for (int m = 1; m < 16; m <<= 1)
    #pragma unroll
    for (int mi = 0; mi < 4; ++mi)
      #pragma unroll
      for (int r = 0; r < 4; ++r) rs[mi][r] += __shfl_xor(rs[mi][r], m, 64);
  if ((lane & 15) == 0) {
    int rloc = wm * 64 + (lane >> 4) * 4;
    #pragma unroll
    for (int mi = 0; mi < 4; ++mi)
      #pragma unroll
      for (int r = 0; r < 4; ++r)
        atomicAdd(&redbuf[rloc + mi * 16 + r], rs[mi][r]);   // 2-way (wn) LDS combine
  }

  // col sums for symmetric off-diagonal blocks: sum over mi,r, reduce across
  // the 4 row-lane-groups (xor 16,32); lanes 0..15 hold col ni*16+lane
  bool do_cols = sym && nb > mb;
  if (do_cols) {
    float cs[4];
    #pragma unroll
    for (int ni = 0; ni < 4; ++ni) {
      cs[ni] = 0.f;
      #pragma unroll
      for (int mi = 0; mi < 4; ++mi)
        #pragma unroll
        for (int r = 0; r < 4; ++r) cs[ni] += acc[mi][ni][r];
    }
    #pragma unroll
    for (int m = 16; m < 64; m <<= 1)
      #pragma unroll
      for (int ni = 0; ni < 4; ++ni) cs[ni] += __shfl_xor(cs[ni], m, 64);
    if (lane < 16) {
      #pragma unroll
      for (int ni = 0; ni < 4; ++ni)
        atomicAdd(&redbuf[128 + wn * 64 + ni * 16 + lane], cs[ni]);  // 2-way (wm) combine
    }
  }
  __syncthreads();

  // one global atomic per row / per col for the whole block
  if (tid < 128)
    atomicAdd(&rowsum[pair * N_ROWS + mb * BM + tid], redbuf[tid]);
  else if (do_cols)
    atomicAdd(&rowsum[pair * N_ROWS + nb * BM + (tid - 128)], redbuf[tid]);
}

// ------- Kernel 3: loss = sum over rows of log(S) - pos -------
__global__ void k_reduce(const short* __restrict__ xn, const short* __restrict__ yn,
                         const float* __restrict__ rowsum, float* __restrict__ out) {
  int tid = threadIdx.x, lane = tid & 63, wid = tid >> 6;
  int gw = blockIdx.x * 4 + wid;  // 0..1023
  float acc = 0.f;
  for (int r = gw; r < 3 * N_ROWS; r += 1024) {
    int pair = r / N_ROWS;
    int n = r - pair * N_ROWS;
    const short* a = (pair == 2) ? yn : xn;
    const short* b = (pair == 0) ? xn : yn;
    short4v av = *(const short4v*)(a + n * DIM + lane * 4);
    short4v bv = *(const short4v*)(b + n * DIM + lane * 4);
    float dot = bf2f(av.x) * bf2f(bv.x) + bf2f(av.y) * bf2f(bv.y) +
                bf2f(av.z) * bf2f(bv.z) + bf2f(av.w) * bf2f(bv.w);
    #pragma unroll
    for (int m = 1; m < 64; m <<= 1) dot += __shfl_xor(dot, m, 64);
    if (lane == 0) acc += logf(rowsum[r]) - dot;
  }
  __shared__ float tmp[4];
  if (lane == 0) tmp[wid] = acc;
  __syncthreads();
  if (tid == 0) atomicAdd(out, tmp[0] + tmp[1] + tmp[2] + tmp[3]);
}

extern "C" void kernel_launch(void* const* d_in, const int* in_sizes, int n_in,
                              void* d_out, int out_size, void* d_ws, size_t ws_size,
                              hipStream_t stream) {
  const float* x = (const float*)d_in[0];
  const float* y = (const float*)d_in[1];
  short* xn = (short*)d_ws;
  short* yn = xn + N_ROWS * DIM;
  float* rowsum = (float*)(yn + N_ROWS * DIM);
  float* out = (float*)d_out;

  // Defensive: never scribble past the workspace. If ws is too small, skip
  // (harness reports a clean verify-fail instead of a wedged container).
  size_t need = (size_t)2 * N_ROWS * DIM * sizeof(short) + 3 * N_ROWS * sizeof(float);
  if (ws_size < need) return;

  hipMemsetAsync(rowsum, 0, 3 * N_ROWS * sizeof(float), stream);
  hipMemsetAsync(out, 0, sizeof(float), stream);
  k_normalize<<<4096, 256, 0, stream>>>(x, y, xn, yn);
  k_gemm<<<12288, 256, 0, stream>>>(xn, yn, rowsum);
  k_reduce<<<256, 256, 0, stream>>>(xn, yn, rowsum, out);
}

// Round 7
// 218.672 us; speedup vs baseline: 1.2168x; 1.2168x over previous
//
#include <hip/hip_runtime.h>
#include <hip/hip_bf16.h>

// ContrastiveLoss on MI355X.
// ws layout (requires ws_size >= 8MB + 96KB):
//   [0, 4MB)        xn bf16 [8192][256]
//   [4MB, 8MB)      yn bf16 [8192][256]
//   [8MB, 8MB+96KB) rowsum f32 [3][8192]

#define N_ROWS 8192
#define DIM 256
#define EPSF 1e-8f
#define BM 128
#define BK 64
#define TILE (BM * BK)

typedef __attribute__((ext_vector_type(8))) short bf16x8;
typedef __attribute__((ext_vector_type(4))) float f32x4;
typedef __attribute__((ext_vector_type(4))) short short4v;

__device__ __forceinline__ short f2bf(float f) {
  unsigned u = __float_as_uint(f);
  unsigned r = (u + 0x7fffu + ((u >> 16) & 1u)) >> 16;  // RNE
  return (short)r;
}

__device__ __forceinline__ float bf2f(short s) {
  return __uint_as_float(((unsigned)(unsigned short)s) << 16);
}

typedef const __attribute__((address_space(1))) void g_void;
typedef __attribute__((address_space(3))) void s_void;

__device__ __forceinline__ void gld_lds16(const void* g, void* l) {
  __builtin_amdgcn_global_load_lds((g_void*)g, (s_void*)l, 16, 0, 0);
}

// ---- Kernel 1: row-normalize x,y -> bf16; also zero rowsum and out ----
__global__ void k_normalize(const float* __restrict__ x, const float* __restrict__ y,
                            short* __restrict__ xn, short* __restrict__ yn,
                            float* __restrict__ rowsum, float* __restrict__ out) {
  // fused zero-init (replaces two hipMemsetAsync dispatches)
  if (blockIdx.x < 96) rowsum[blockIdx.x * 256 + threadIdx.x] = 0.f;  // 96*256 = 24576
  if (blockIdx.x == 96 && threadIdx.x == 0) out[0] = 0.f;

  int wave = threadIdx.x >> 6;
  int lane = threadIdx.x & 63;
  int row = blockIdx.x * 4 + wave;  // 0..16383
  const float* src;
  short* dst;
  int r;
  if (row < N_ROWS) { src = x; dst = xn; r = row; }
  else              { src = y; dst = yn; r = row - N_ROWS; }
  const float4 v = *(const float4*)(src + r * DIM + lane * 4);
  float ss = v.x * v.x + v.y * v.y + v.z * v.z + v.w * v.w;
  #pragma unroll
  for (int m = 1; m < 64; m <<= 1) ss += __shfl_xor(ss, m, 64);
  float scale = 1.0f / (sqrtf(ss) + EPSF);
  short4v o;
  o.x = f2bf(v.x * scale);
  o.y = f2bf(v.y * scale);
  o.z = f2bf(v.z * scale);
  o.w = f2bf(v.w * scale);
  *(short4v*)(dst + r * DIM + lane * 4) = o;
}

// ------- Kernel 2: sim tile (bf16 MFMA) + exp + row-partial sums -------
// COMPACT grid: 8256 blocks = 2*2080 (upper-tri xx,yy) + 4096 (xy), all
// productive. 8256 = 8*1032 -> exact XCD balance with chunked swizzle.
// 2-phase double-buffered staging (stage next || compute cur, 1 barrier/step).
// LDS bank conflicts fixed by XOR-swizzled STAGING SOURCE + same XOR on read
// (rule #21: global_load_lds dest stays linear; source & read share involution).
// LDS held to exactly 64KB: epilogue redbuf aliases As (barrier-guarded).
__global__ __launch_bounds__(256, 2) void k_gemm(const short* __restrict__ xn,
                                                 const short* __restrict__ yn,
                                                 float* __restrict__ rowsum) {
  __shared__ __align__(16) short As[2 * TILE];   // 32KB
  __shared__ __align__(16) short Bs[2 * TILE];   // 32KB

  int bid = blockIdx.x;
  int swz = (bid & 7) * 1032 + (bid >> 3);  // XCD-chunked, bijective (8256%8==0)

  // unrank compact id -> (pair, mb, nb)
  int pair, mb, nb;
  if (swz < 4160) {                         // symmetric pairs, upper triangle
    pair = (swz < 2080) ? 0 : 2;
    int t = (swz < 2080) ? swz : swz - 2080;
    int r = 0;
    while (t >= 64 - r) { t -= 64 - r; ++r; }  // block-uniform, <=64 iters
    mb = r; nb = r + t;
  } else {                                  // xy: full 64x64
    pair = 1;
    int t = swz - 4160;
    mb = t >> 6; nb = t & 63;
  }

  const short* Ap = (pair == 2) ? yn : xn;
  const short* Bp = (pair == 0) ? xn : yn;
  const short* Abase = Ap + mb * BM * DIM;
  const short* Bbase = Bp + nb * BM * DIM;

  int tid = threadIdx.x;
  int lane = tid & 63;
  int wid = tid >> 6;
  int wm = wid >> 1, wn = wid & 1;

  f32x4 acc[4][4];
  #pragma unroll
  for (int i = 0; i < 4; ++i)
    #pragma unroll
    for (int j = 0; j < 4; ++j) acc[i][j] = (f32x4){0.f, 0.f, 0.f, 0.f};

  // stage one [128][64] tile pair into buffer `buf`; LDS slot s=(row,c) holds
  // global slot c^(row&7)  (involution; read applies the same XOR)
  auto stage = [&](int buf, int koff) {
    #pragma unroll
    for (int i = 0; i < 4; ++i) {
      int s = i * 256 + tid;         // 16B slot id
      int row = s >> 3, c = s & 7;
      int cs = c ^ (row & 7);
      gld_lds16(Abase + row * DIM + koff + cs * 8, As + buf * TILE + s * 8);
      gld_lds16(Bbase + row * DIM + koff + cs * 8, Bs + buf * TILE + s * 8);
    }
  };

  auto compute = [&](int buf) {
    #pragma unroll
    for (int kk = 0; kk < 2; ++kk) {
      bf16x8 a[4], b[4];
      #pragma unroll
      for (int mi = 0; mi < 4; ++mi) {
        int row = wm * 64 + mi * 16 + (lane & 15);       // row&7 == lane&7
        int slot = (kk * 4 + (lane >> 4)) ^ (lane & 7);  // swizzled 16B slot
        a[mi] = *(const bf16x8*)(As + buf * TILE + row * BK + slot * 8);
      }
      #pragma unroll
      for (int ni = 0; ni < 4; ++ni) {
        int row = wn * 64 + ni * 16 + (lane & 15);
        int slot = (kk * 4 + (lane >> 4)) ^ (lane & 7);
        b[ni] = *(const bf16x8*)(Bs + buf * TILE + row * BK + slot * 8);
      }
      #pragma unroll
      for (int mi = 0; mi < 4; ++mi)
        #pragma unroll
        for (int ni = 0; ni < 4; ++ni)
          acc[mi][ni] = __builtin_amdgcn_mfma_f32_16x16x32_bf16(a[mi], b[ni], acc[mi][ni], 0, 0, 0);
    }
  };

  // 2-phase pipeline over DIM/BK = 4 K-steps
  stage(0, 0);
  __syncthreads();                       // vmcnt(0) drain for buf0
  #pragma unroll
  for (int ks = 0; ks < 4; ++ks) {
    if (ks < 3) stage((ks + 1) & 1, (ks + 1) * BK);  // loads fly during compute
    compute(ks & 1);
    if (ks < 3) __syncthreads();         // drains next-tile vmcnt + this lgkm
  }

  // epilogue: exp in place, then row sums (and col sums for sym off-diag)
  // C layout (m89): col = lane&15, row = (lane>>4)*4 + r
  // global: row = mb*128 + wm*64 + mi*16 + (lane>>4)*4 + r
  //         col = nb*128 + wn*64 + ni*16 + (lane&15)
  #pragma unroll
  for (int mi = 0; mi < 4; ++mi)
    #pragma unroll
    for (int ni = 0; ni < 4; ++ni)
      #pragma unroll
      for (int r = 0; r < 4; ++r)
        acc[mi][ni][r] = __expf(acc[mi][ni][r]);

  float rs[4][4];
  #pragma unroll
  for (int mi = 0; mi < 4; ++mi)
    #pragma unroll
    for (int r = 0; r < 4; ++r)
      rs[mi][r] = acc[mi][0][r] + acc[mi][1][r] + acc[mi][2][r] + acc[mi][3][r];
  #pragma unroll
  for (int m = 1; m < 16; m <<= 1)
    #pragma unroll
    for (int mi = 0; mi < 4; ++mi)
      #pragma unroll
      for (int r = 0; r < 4; ++r) rs[mi][r] += __shfl_xor(rs[mi][r], m, 64);

  bool do_cols = (pair != 1) && (nb > mb);
  float cs[4];
  if (do_cols) {
    #pragma unroll
    for (int ni = 0; ni < 4; ++ni) {
      cs[ni] = 0.f;
      #pragma unroll
      for (int mi = 0; mi < 4; ++mi)
        #pragma unroll
        for (int r = 0; r < 4; ++r) cs[ni] += acc[mi][ni][r];
    }
    #pragma unroll
    for (int m = 16; m < 64; m <<= 1)
      #pragma unroll
      for (int ni = 0; ni < 4; ++ni) cs[ni] += __shfl_xor(cs[ni], m, 64);
  }

  // redbuf aliases As (all LDS reads done after this barrier)
  float* redbuf = (float*)As;  // [0:128) row partials, [128:256) col partials
  __syncthreads();
  redbuf[tid] = 0.f;
  __syncthreads();

  if ((lane & 15) == 0) {
    int rloc = wm * 64 + (lane >> 4) * 4;
    #pragma unroll
    for (int mi = 0; mi < 4; ++mi)
      #pragma unroll
      for (int r = 0; r < 4; ++r)
        atomicAdd(&redbuf[rloc + mi * 16 + r], rs[mi][r]);   // 2-way (wn) combine
  }
  if (do_cols && lane < 16) {
    #pragma unroll
    for (int ni = 0; ni < 4; ++ni)
      atomicAdd(&redbuf[128 + wn * 64 + ni * 16 + lane], cs[ni]);  // 2-way (wm)
  }
  __syncthreads();

  // one global atomic per row / per col for the whole block
  if (tid < 128)
    atomicAdd(&rowsum[pair * N_ROWS + mb * BM + tid], redbuf[tid]);
  else if (do_cols)
    atomicAdd(&rowsum[pair * N_ROWS + nb * BM + (tid - 128)], redbuf[tid]);
}

// ------- Kernel 3: loss = sum over rows of log(S) - pos -------
__global__ void k_reduce(const short* __restrict__ xn, const short* __restrict__ yn,
                         const float* __restrict__ rowsum, float* __restrict__ out) {
  int tid = threadIdx.x, lane = tid & 63, wid = tid >> 6;
  int gw = blockIdx.x * 4 + wid;  // 0..1023
  float acc = 0.f;
  for (int r = gw; r < 3 * N_ROWS; r += 1024) {
    int pair = r / N_ROWS;
    int n = r - pair * N_ROWS;
    const short* a = (pair == 2) ? yn : xn;
    const short* b = (pair == 0) ? xn : yn;
    short4v av = *(const short4v*)(a + n * DIM + lane * 4);
    short4v bv = *(const short4v*)(b + n * DIM + lane * 4);
    float dot = bf2f(av.x) * bf2f(bv.x) + bf2f(av.y) * bf2f(bv.y) +
                bf2f(av.z) * bf2f(bv.z) + bf2f(av.w) * bf2f(bv.w);
    #pragma unroll
    for (int m = 1; m < 64; m <<= 1) dot += __shfl_xor(dot, m, 64);
    if (lane == 0) acc += logf(rowsum[r]) - dot;
  }
  __shared__ float tmp[4];
  if (lane == 0) tmp[wid] = acc;
  __syncthreads();
  if (tid == 0) atomicAdd(out, tmp[0] + tmp[1] + tmp[2] + tmp[3]);
}

extern "C" void kernel_launch(void* const* d_in, const int* in_sizes, int n_in,
                              void* d_out, int out_size, void* d_ws, size_t ws_size,
                              hipStream_t stream) {
  const float* x = (const float*)d_in[0];
  const float* y = (const float*)d_in[1];
  short* xn = (short*)d_ws;
  short* yn = xn + N_ROWS * DIM;
  float* rowsum = (float*)(yn + N_ROWS * DIM);
  float* out = (float*)d_out;

  size_t need = (size_t)2 * N_ROWS * DIM * sizeof(short) + 3 * N_ROWS * sizeof(float);
  if (ws_size < need) return;

  k_normalize<<<4096, 256, 0, stream>>>(x, y, xn, yn, rowsum, out);
  k_gemm<<<8256, 256, 0, stream>>>(xn, yn, rowsum);
  k_reduce<<<256, 256, 0, stream>>>(xn, yn, rowsum, out);
}

// Round 8
// 204.887 us; speedup vs baseline: 1.2986x; 1.0673x over previous
//
#include <hip/hip_runtime.h>
#include <hip/hip_bf16.h>

// ContrastiveLoss on MI355X.
// ws layout (requires ws_size >= 8MB + 96KB):
//   [0, 4MB)        xn bf16 [8192][256]
//   [4MB, 8MB)      yn bf16 [8192][256]
//   [8MB, 8MB+96KB) rowsum f32 [3][8192]

#define N_ROWS 8192
#define DIM 256
#define EPSF 1e-8f
#define BM 128
#define BK 32
#define TILE (BM * BK)   // 4096 shorts = 8KB

typedef __attribute__((ext_vector_type(8))) short bf16x8;
typedef __attribute__((ext_vector_type(4))) float f32x4;
typedef __attribute__((ext_vector_type(4))) short short4v;

__device__ __forceinline__ short f2bf(float f) {
  unsigned u = __float_as_uint(f);
  unsigned r = (u + 0x7fffu + ((u >> 16) & 1u)) >> 16;  // RNE
  return (short)r;
}

__device__ __forceinline__ float bf2f(short s) {
  return __uint_as_float(((unsigned)(unsigned short)s) << 16);
}

typedef const __attribute__((address_space(1))) void g_void;
typedef __attribute__((address_space(3))) void s_void;

__device__ __forceinline__ void gld_lds16(const void* g, void* l) {
  __builtin_amdgcn_global_load_lds((g_void*)g, (s_void*)l, 16, 0, 0);
}

// ---- Kernel 1: row-normalize x,y -> bf16; also zero rowsum and out ----
__global__ void k_normalize(const float* __restrict__ x, const float* __restrict__ y,
                            short* __restrict__ xn, short* __restrict__ yn,
                            float* __restrict__ rowsum, float* __restrict__ out) {
  if (blockIdx.x < 96) rowsum[blockIdx.x * 256 + threadIdx.x] = 0.f;  // 96*256 = 24576
  if (blockIdx.x == 96 && threadIdx.x == 0) out[0] = 0.f;

  int wave = threadIdx.x >> 6;
  int lane = threadIdx.x & 63;
  int row = blockIdx.x * 4 + wave;  // 0..16383
  const float* src;
  short* dst;
  int r;
  if (row < N_ROWS) { src = x; dst = xn; r = row; }
  else              { src = y; dst = yn; r = row - N_ROWS; }
  const float4 v = *(const float4*)(src + r * DIM + lane * 4);
  float ss = v.x * v.x + v.y * v.y + v.z * v.z + v.w * v.w;
  #pragma unroll
  for (int m = 1; m < 64; m <<= 1) ss += __shfl_xor(ss, m, 64);
  float scale = 1.0f / (sqrtf(ss) + EPSF);
  short4v o;
  o.x = f2bf(v.x * scale);
  o.y = f2bf(v.y * scale);
  o.z = f2bf(v.z * scale);
  o.w = f2bf(v.w * scale);
  *(short4v*)(dst + r * DIM + lane * 4) = o;
}

// ------- Kernel 2: sim tile (bf16 MFMA) + exp + row-partial sums -------
// COMPACT grid: 8256 blocks = 2*2080 (upper-tri xx,yy) + 4096 (xy), all
// productive; 8256 = 8*1032 -> exact XCD balance with chunked swizzle.
// BK=32 double-buffer: LDS = 33KB -> 4 blocks/CU (16 waves, ~50% occ), the
// TLP that round-7 counters showed was missing (19% occ, 2.3x pipe floor).
// Bank-conflict-free via source-side XOR: cs = c ^ (row&3) ^ ((row>>2)&3)
// (rule #21: linear global_load_lds dest; same involution on read; traced
// to 2-way = free).
__global__ __launch_bounds__(256, 4) void k_gemm(const short* __restrict__ xn,
                                                 const short* __restrict__ yn,
                                                 float* __restrict__ rowsum) {
  __shared__ __align__(16) short As[2 * TILE];   // 16KB
  __shared__ __align__(16) short Bs[2 * TILE];   // 16KB
  __shared__ float redbuf[256];                  // 1KB

  int bid = blockIdx.x;
  int swz = (bid & 7) * 1032 + (bid >> 3);  // XCD-chunked, bijective (8256%8==0)

  // unrank compact id -> (pair, mb, nb)
  int pair, mb, nb;
  if (swz < 4160) {                         // symmetric pairs, upper triangle
    pair = (swz < 2080) ? 0 : 2;
    int t = (swz < 2080) ? swz : swz - 2080;
    int r = 0;
    while (t >= 64 - r) { t -= 64 - r; ++r; }  // block-uniform, <=64 iters
    mb = r; nb = r + t;
  } else {                                  // xy: full 64x64
    pair = 1;
    int t = swz - 4160;
    mb = t >> 6; nb = t & 63;
  }

  const short* Ap = (pair == 2) ? yn : xn;
  const short* Bp = (pair == 0) ? xn : yn;
  const short* Abase = Ap + mb * BM * DIM;
  const short* Bbase = Bp + nb * BM * DIM;

  int tid = threadIdx.x;
  int lane = tid & 63;
  int wid = tid >> 6;
  int wm = wid >> 1, wn = wid & 1;

  redbuf[tid] = 0.f;  // ordered by the prologue barrier

  f32x4 acc[4][4];
  #pragma unroll
  for (int i = 0; i < 4; ++i)
    #pragma unroll
    for (int j = 0; j < 4; ++j) acc[i][j] = (f32x4){0.f, 0.f, 0.f, 0.f};

  // stage one [128][32] tile pair into buffer `buf`; LDS 16B-slot (row,c)
  // holds global slot c ^ (row&3) ^ ((row>>2)&3)
  auto stage = [&](int buf, int koff) {
    #pragma unroll
    for (int i = 0; i < 2; ++i) {
      int s = i * 256 + tid;         // 16B slot id, 512 per tile
      int row = s >> 2, c = s & 3;
      int cs = c ^ (row & 3) ^ ((row >> 2) & 3);
      gld_lds16(Abase + row * DIM + koff + cs * 8, As + buf * TILE + s * 8);
      gld_lds16(Bbase + row * DIM + koff + cs * 8, Bs + buf * TILE + s * 8);
    }
  };

  // fragment slot for k-group (lane>>4), applying the same involution;
  // row low bits == lane low bits for every fragment row
  int fslot = (lane >> 4) ^ (lane & 3) ^ ((lane >> 2) & 3);

  auto compute = [&](int buf) {
    bf16x8 a[4], b[4];
    #pragma unroll
    for (int mi = 0; mi < 4; ++mi) {
      int row = wm * 64 + mi * 16 + (lane & 15);
      a[mi] = *(const bf16x8*)(As + buf * TILE + row * BK + fslot * 8);
    }
    #pragma unroll
    for (int ni = 0; ni < 4; ++ni) {
      int row = wn * 64 + ni * 16 + (lane & 15);
      b[ni] = *(const bf16x8*)(Bs + buf * TILE + row * BK + fslot * 8);
    }
    #pragma unroll
    for (int mi = 0; mi < 4; ++mi)
      #pragma unroll
      for (int ni = 0; ni < 4; ++ni)
        acc[mi][ni] = __builtin_amdgcn_mfma_f32_16x16x32_bf16(a[mi], b[ni], acc[mi][ni], 0, 0, 0);
  };

  // 2-phase pipeline over DIM/BK = 8 K-steps
  stage(0, 0);
  __syncthreads();                       // vmcnt(0) drain for buf0
  #pragma unroll
  for (int ks = 0; ks < 8; ++ks) {
    if (ks < 7) stage((ks + 1) & 1, (ks + 1) * BK);  // loads fly during compute
    compute(ks & 1);
    if (ks < 7) __syncthreads();
  }

  // epilogue: exp in place, then row sums (and col sums for sym off-diag)
  // C layout (m89): col = lane&15, row = (lane>>4)*4 + r
  // global: row = mb*128 + wm*64 + mi*16 + (lane>>4)*4 + r
  //         col = nb*128 + wn*64 + ni*16 + (lane&15)
  #pragma unroll
  for (int mi = 0; mi < 4; ++mi)
    #pragma unroll
    for (int ni = 0; ni < 4; ++ni)
      #pragma unroll
      for (int r = 0; r < 4; ++r)
        acc[mi][ni][r] = __expf(acc[mi][ni][r]);

  float rs[4][4];
  #pragma unroll
  for (int mi = 0; mi < 4; ++mi)
    #pragma unroll
    for (int r = 0; r < 4; ++r)
      rs[mi][r] = acc[mi][0][r] + acc[mi][1][r] + acc[mi][2][r] + acc[mi][3][r];
  #pragma unroll
  for (int m = 1; m < 16; m <<= 1)
    #pragma unroll
    for (int mi = 0; mi < 4; ++mi)
      #pragma unroll
      for (int r = 0; r < 4; ++r) rs[mi][r] += __shfl_xor(rs[mi][r], m, 64);
  if ((lane & 15) == 0) {
    int rloc = wm * 64 + (lane >> 4) * 4;
    #pragma unroll
    for (int mi = 0; mi < 4; ++mi)
      #pragma unroll
      for (int r = 0; r < 4; ++r)
        atomicAdd(&redbuf[rloc + mi * 16 + r], rs[mi][r]);   // 2-way (wn) combine
  }

  bool do_cols = (pair != 1) && (nb > mb);
  if (do_cols) {
    float cs[4];
    #pragma unroll
    for (int ni = 0; ni < 4; ++ni) {
      cs[ni] = 0.f;
      #pragma unroll
      for (int mi = 0; mi < 4; ++mi)
        #pragma unroll
        for (int r = 0; r < 4; ++r) cs[ni] += acc[mi][ni][r];
    }
    #pragma unroll
    for (int m = 16; m < 64; m <<= 1)
      #pragma unroll
      for (int ni = 0; ni < 4; ++ni) cs[ni] += __shfl_xor(cs[ni], m, 64);
    if (lane < 16) {
      #pragma unroll
      for (int ni = 0; ni < 4; ++ni)
        atomicAdd(&redbuf[128 + wn * 64 + ni * 16 + lane], cs[ni]);  // 2-way (wm)
    }
  }
  __syncthreads();

  // one global atomic per row / per col for the whole block
  if (tid < 128)
    atomicAdd(&rowsum[pair * N_ROWS + mb * BM + tid], redbuf[tid]);
  else if (do_cols)
    atomicAdd(&rowsum[pair * N_ROWS + nb * BM + (tid - 128)], redbuf[tid]);
}

// ------- Kernel 3: loss = sum over rows of log(S) - pos -------
__global__ void k_reduce(const short* __restrict__ xn, const short* __restrict__ yn,
                         const float* __restrict__ rowsum, float* __restrict__ out) {
  int tid = threadIdx.x, lane = tid & 63, wid = tid >> 6;
  int gw = blockIdx.x * 4 + wid;  // 0..1023
  float acc = 0.f;
  for (int r = gw; r < 3 * N_ROWS; r += 1024) {
    int pair = r / N_ROWS;
    int n = r - pair * N_ROWS;
    const short* a = (pair == 2) ? yn : xn;
    const short* b = (pair == 0) ? xn : yn;
    short4v av = *(const short4v*)(a + n * DIM + lane * 4);
    short4v bv = *(const short4v*)(b + n * DIM + lane * 4);
    float dot = bf2f(av.x) * bf2f(bv.x) + bf2f(av.y) * bf2f(bv.y) +
                bf2f(av.z) * bf2f(bv.z) + bf2f(av.w) * bf2f(bv.w);
    #pragma unroll
    for (int m = 1; m < 64; m <<= 1) dot += __shfl_xor(dot, m, 64);
    if (lane == 0) acc += logf(rowsum[r]) - dot;
  }
  __shared__ float tmp[4];
  if (lane == 0) tmp[wid] = acc;
  __syncthreads();
  if (tid == 0) atomicAdd(out, tmp[0] + tmp[1] + tmp[2] + tmp[3]);
}

extern "C" void kernel_launch(void* const* d_in, const int* in_sizes, int n_in,
                              void* d_out, int out_size, void* d_ws, size_t ws_size,
                              hipStream_t stream) {
  const float* x = (const float*)d_in[0];
  const float* y = (const float*)d_in[1];
  short* xn = (short*)d_ws;
  short* yn = xn + N_ROWS * DIM;
  float* rowsum = (float*)(yn + N_ROWS * DIM);
  float* out = (float*)d_out;

  size_t need = (size_t)2 * N_ROWS * DIM * sizeof(short) + 3 * N_ROWS * sizeof(float);
  if (ws_size < need) return;

  k_normalize<<<4096, 256, 0, stream>>>(x, y, xn, yn, rowsum, out);
  k_gemm<<<8256, 256, 0, stream>>>(xn, yn, rowsum);
  k_reduce<<<256, 256, 0, stream>>>(xn, yn, rowsum, out);
}

// Round 9
// 190.023 us; speedup vs baseline: 1.4002x; 1.0782x over previous
//
#include <hip/hip_runtime.h>
#include <hip/hip_bf16.h>

// ContrastiveLoss on MI355X.
// ws layout (requires ws_size >= 8MB + 96KB):
//   [0, 4MB)        xn bf16 [8192][256]
//   [4MB, 8MB)      yn bf16 [8192][256]
//   [8MB, 8MB+96KB) rowsum f32 [3][8192]

#define N_ROWS 8192
#define DIM 256
#define EPSF 1e-8f
#define BM 128
#define BN 256
#define BK 32
#define ATILE (BM * BK)   // 4096 shorts = 8KB
#define BTILE (BN * BK)   // 8192 shorts = 16KB

typedef __attribute__((ext_vector_type(8))) short bf16x8;
typedef __attribute__((ext_vector_type(4))) float f32x4;
typedef __attribute__((ext_vector_type(4))) short short4v;

__device__ __forceinline__ short f2bf(float f) {
  unsigned u = __float_as_uint(f);
  unsigned r = (u + 0x7fffu + ((u >> 16) & 1u)) >> 16;  // RNE
  return (short)r;
}

__device__ __forceinline__ float bf2f(short s) {
  return __uint_as_float(((unsigned)(unsigned short)s) << 16);
}

typedef const __attribute__((address_space(1))) void g_void;
typedef __attribute__((address_space(3))) void s_void;

__device__ __forceinline__ void gld_lds16(const void* g, void* l) {
  __builtin_amdgcn_global_load_lds((g_void*)g, (s_void*)l, 16, 0, 0);
}

// ---- Kernel 1: row-normalize x,y -> bf16; also zero rowsum and out ----
__global__ void k_normalize(const float* __restrict__ x, const float* __restrict__ y,
                            short* __restrict__ xn, short* __restrict__ yn,
                            float* __restrict__ rowsum, float* __restrict__ out) {
  if (blockIdx.x < 96) rowsum[blockIdx.x * 256 + threadIdx.x] = 0.f;  // 96*256 = 24576
  if (blockIdx.x == 96 && threadIdx.x == 0) out[0] = 0.f;

  int wave = threadIdx.x >> 6;
  int lane = threadIdx.x & 63;
  int row = blockIdx.x * 4 + wave;  // 0..16383
  const float* src;
  short* dst;
  int r;
  if (row < N_ROWS) { src = x; dst = xn; r = row; }
  else              { src = y; dst = yn; r = row - N_ROWS; }
  const float4 v = *(const float4*)(src + r * DIM + lane * 4);
  float ss = v.x * v.x + v.y * v.y + v.z * v.z + v.w * v.w;
  #pragma unroll
  for (int m = 1; m < 64; m <<= 1) ss += __shfl_xor(ss, m, 64);
  float scale = 1.0f / (sqrtf(ss) + EPSF);
  short4v o;
  o.x = f2bf(v.x * scale);
  o.y = f2bf(v.y * scale);
  o.z = f2bf(v.z * scale);
  o.w = f2bf(v.w * scale);
  *(short4v*)(dst + r * DIM + lane * 4) = o;
}

// ------- Kernel 2: sim tile (bf16 MFMA) + exp + row/col partial sums -------
// Block tile 128x256 (4 waves, wave tile 64x128, acc 4x8) -- LDS-pipe math:
// fragment reads per MFMA drop 1.5x vs 128x128, lifting the MfmaUtil ceiling
// (r8 counters showed 22% = the 128x128 LDS-bound ceiling).
// Grid 4160 = 2*1056 (sym pairs, col-tiles 256 wide, straddle-masked) + 2048
// (xy); 4160 = 8*520 -> exact XCD balance. BK=32 double-buffered (49.5KB LDS).
// Involution slot ^= (row>>1)&3: 16-lane fragment-read group covers all 8
// 16B-windows -> conflict-free (r8's (row&3)^((row>>2)&3) was 4-way).
__global__ __launch_bounds__(256, 2) void k_gemm(const short* __restrict__ xn,
                                                 const short* __restrict__ yn,
                                                 float* __restrict__ rowsum) {
  __shared__ __align__(16) short As[2 * ATILE];   // 16KB
  __shared__ __align__(16) short Bs[2 * BTILE];   // 32KB
  __shared__ float redbuf[384];                   // rows [0:128), cols [128:384)

  int bid = blockIdx.x;
  int swz = (bid & 7) * 520 + (bid >> 3);   // XCD-chunked, bijective (4160%8==0)

  // unrank -> (pair, mb [128-row tile], nb [256-col tile])
  int pair, mb, nb;
  if (swz < 2112) {                          // symmetric pairs: mb <= 2nb+1
    pair = (swz < 1056) ? 0 : 2;
    int t = (swz < 1056) ? swz : swz - 1056;
    int nbi = 0;
    while (true) {                           // block-uniform, <=32 iters
      int cnt = 2 * nbi + 2;                 // min(2nb+2,64) == 2nb+2 for nb<=31
      if (t < cnt) { mb = t; break; }
      t -= cnt; ++nbi;
    }
    nb = nbi;
  } else {
    pair = 1;
    int t = swz - 2112;
    mb = t >> 5; nb = t & 31;
  }

  bool sym = (pair != 1);
  // half validity (c0 = 2nb, c1 = 2nb+1 in 128-col units)
  bool l_row = !(sym && (mb == 2 * nb + 1));  // left half strictly below diag -> drop
  bool l_col = sym && (2 * nb > mb);
  bool r_col = sym && (2 * nb + 1 > mb);

  const short* Ap = (pair == 2) ? yn : xn;
  const short* Bp = (pair == 0) ? xn : yn;
  const short* Abase = Ap + mb * BM * DIM;
  const short* Bbase = Bp + nb * BN * DIM;

  int tid = threadIdx.x;
  int lane = tid & 63;
  int wid = tid >> 6;
  int wm = wid >> 1, wn = wid & 1;

  redbuf[tid] = 0.f;
  if (tid < 128) redbuf[256 + tid] = 0.f;

  f32x4 acc[4][8];
  #pragma unroll
  for (int i = 0; i < 4; ++i)
    #pragma unroll
    for (int j = 0; j < 8; ++j) acc[i][j] = (f32x4){0.f, 0.f, 0.f, 0.f};

  // stage A[128][32] + B[256][32] into buffer `buf`; LDS 16B-slot (row,c)
  // holds global chunk c ^ ((row>>1)&3)  (linear dest per rule #21)
  auto stage = [&](int buf, int koff) {
    #pragma unroll
    for (int i = 0; i < 2; ++i) {
      int s = i * 256 + tid;           // A: 512 slots
      int row = s >> 2, c = s & 3;
      int cs = c ^ ((row >> 1) & 3);
      gld_lds16(Abase + row * DIM + koff + cs * 8, As + buf * ATILE + s * 8);
    }
    #pragma unroll
    for (int i = 0; i < 4; ++i) {
      int s = i * 256 + tid;           // B: 1024 slots
      int row = s >> 2, c = s & 3;
      int cs = c ^ ((row >> 1) & 3);
      gld_lds16(Bbase + row * DIM + koff + cs * 8, Bs + buf * BTILE + s * 8);
    }
  };

  // fragment slot: global k-chunk (lane>>4), same involution (row&15==lane&15)
  int fslot = (lane >> 4) ^ ((lane >> 1) & 3);

  auto compute = [&](int buf) {
    bf16x8 a[4], b[8];
    #pragma unroll
    for (int mi = 0; mi < 4; ++mi) {
      int row = wm * 64 + mi * 16 + (lane & 15);
      a[mi] = *(const bf16x8*)(As + buf * ATILE + row * BK + fslot * 8);
    }
    #pragma unroll
    for (int ni = 0; ni < 8; ++ni) {
      int row = wn * 128 + ni * 16 + (lane & 15);
      b[ni] = *(const bf16x8*)(Bs + buf * BTILE + row * BK + fslot * 8);
    }
    #pragma unroll
    for (int mi = 0; mi < 4; ++mi)
      #pragma unroll
      for (int ni = 0; ni < 8; ++ni)
        acc[mi][ni] = __builtin_amdgcn_mfma_f32_16x16x32_bf16(a[mi], b[ni], acc[mi][ni], 0, 0, 0);
  };

  // 2-phase pipeline over DIM/BK = 8 K-steps
  stage(0, 0);
  __syncthreads();
  #pragma unroll
  for (int ks = 0; ks < 8; ++ks) {
    if (ks < 7) stage((ks + 1) & 1, (ks + 1) * BK);
    compute(ks & 1);
    if (ks < 7) __syncthreads();
  }

  // epilogue: exp in place; row sums (half-masked) + col sums (half-masked)
  // C layout (m89): col = lane&15, row = (lane>>4)*4 + r
  // global row = mb*128 + wm*64 + mi*16 + (lane>>4)*4 + r
  // global col = nb*256 + wn*128 + ni*16 + (lane&15)
  #pragma unroll
  for (int mi = 0; mi < 4; ++mi)
    #pragma unroll
    for (int ni = 0; ni < 8; ++ni)
      #pragma unroll
      for (int r = 0; r < 4; ++r)
        acc[mi][ni][r] = __expf(acc[mi][ni][r]);

  float rs[4][4];
  #pragma unroll
  for (int mi = 0; mi < 4; ++mi)
    #pragma unroll
    for (int r = 0; r < 4; ++r) {
      float sl = acc[mi][0][r] + acc[mi][1][r] + acc[mi][2][r] + acc[mi][3][r];
      float sr = acc[mi][4][r] + acc[mi][5][r] + acc[mi][6][r] + acc[mi][7][r];
      rs[mi][r] = (l_row ? sl : 0.f) + sr;   // right half always row-valid
    }
  #pragma unroll
  for (int m = 1; m < 16; m <<= 1)
    #pragma unroll
    for (int mi = 0; mi < 4; ++mi)
      #pragma unroll
      for (int r = 0; r < 4; ++r) rs[mi][r] += __shfl_xor(rs[mi][r], m, 64);
  if ((lane & 15) == 0) {
    int rloc = wm * 64 + (lane >> 4) * 4;
    #pragma unroll
    for (int mi = 0; mi < 4; ++mi)
      #pragma unroll
      for (int r = 0; r < 4; ++r)
        atomicAdd(&redbuf[rloc + mi * 16 + r], rs[mi][r]);   // 2-way (wn) combine
  }

  if (l_col || r_col) {
    float cs_[8];
    #pragma unroll
    for (int ni = 0; ni < 8; ++ni) {
      cs_[ni] = 0.f;
      #pragma unroll
      for (int mi = 0; mi < 4; ++mi)
        #pragma unroll
        for (int r = 0; r < 4; ++r) cs_[ni] += acc[mi][ni][r];
    }
    #pragma unroll
    for (int m = 16; m < 64; m <<= 1)
      #pragma unroll
      for (int ni = 0; ni < 8; ++ni) cs_[ni] += __shfl_xor(cs_[ni], m, 64);
    if (lane < 16) {
      #pragma unroll
      for (int ni = 0; ni < 8; ++ni)
        if (ni < 4 ? l_col : r_col)
          atomicAdd(&redbuf[128 + wn * 128 + ni * 16 + lane], cs_[ni]);  // 2-way (wm)
    }
  }
  __syncthreads();

  // one global atomic per row / per col for the whole block
  if (tid < 128)
    atomicAdd(&rowsum[pair * N_ROWS + mb * BM + tid], redbuf[tid]);
  bool cvalid = (tid < 128) ? l_col : r_col;
  if (cvalid)
    atomicAdd(&rowsum[pair * N_ROWS + nb * BN + tid], redbuf[128 + tid]);
}

// ------- Kernel 3: loss = sum over rows of log(S) - pos -------
__global__ void k_reduce(const short* __restrict__ xn, const short* __restrict__ yn,
                         const float* __restrict__ rowsum, float* __restrict__ out) {
  int tid = threadIdx.x, lane = tid & 63, wid = tid >> 6;
  int gw = blockIdx.x * 4 + wid;  // 0..1023
  float acc = 0.f;
  for (int r = gw; r < 3 * N_ROWS; r += 1024) {
    int pair = r / N_ROWS;
    int n = r - pair * N_ROWS;
    const short* a = (pair == 2) ? yn : xn;
    const short* b = (pair == 0) ? xn : yn;
    short4v av = *(const short4v*)(a + n * DIM + lane * 4);
    short4v bv = *(const short4v*)(b + n * DIM + lane * 4);
    float dot = bf2f(av.x) * bf2f(bv.x) + bf2f(av.y) * bf2f(bv.y) +
                bf2f(av.z) * bf2f(bv.z) + bf2f(av.w) * bf2f(bv.w);
    #pragma unroll
    for (int m = 1; m < 64; m <<= 1) dot += __shfl_xor(dot, m, 64);
    if (lane == 0) acc += logf(rowsum[r]) - dot;
  }
  __shared__ float tmp[4];
  if (lane == 0) tmp[wid] = acc;
  __syncthreads();
  if (tid == 0) atomicAdd(out, tmp[0] + tmp[1] + tmp[2] + tmp[3]);
}

extern "C" void kernel_launch(void* const* d_in, const int* in_sizes, int n_in,
                              void* d_out, int out_size, void* d_ws, size_t ws_size,
                              hipStream_t stream) {
  const float* x = (const float*)d_in[0];
  const float* y = (const float*)d_in[1];
  short* xn = (short*)d_ws;
  short* yn = xn + N_ROWS * DIM;
  float* rowsum = (float*)(yn + N_ROWS * DIM);
  float* out = (float*)d_out;

  size_t need = (size_t)2 * N_ROWS * DIM * sizeof(short) + 3 * N_ROWS * sizeof(float);
  if (ws_size < need) return;

  k_normalize<<<4096, 256, 0, stream>>>(x, y, xn, yn, rowsum, out);
  k_gemm<<<4160, 256, 0, stream>>>(xn, yn, rowsum);
  k_reduce<<<256, 256, 0, stream>>>(xn, yn, rowsum, out);
}